// Round 2
// 313.811 us; speedup vs baseline: 1.0015x; 1.0015x over previous
//
#include <hip/hip_runtime.h>
#include <hip/hip_bf16.h>

// Decoder layer: self-attn (causal, shared qkv proj) + LN, cross-attn + LN,
// FFN (relu) + LN.  B=1, S=2048, D=1024, H=16, DH=64, HID=4096.
// I/O fp32.  GEMMs + attention bf16 MFMA (16x16x32), fp32 accumulate.
// Fixed-max softmax (|scores| < ~5 => exp never overflows) => split-K
// attention emits unnormalized O + l partials; the next LN merges.
// R12 == R11 resubmit (container infra failure, no counters returned):
// T3-min 2-phase pipeline in GEMM + attention: double-buffered LDS,
// stage(t+1) issued BEFORE compute(t), single __syncthreads (vmcnt drain)
// per tile.  R10 counters: attn MfmaUtil 14%/6.8% at identical 44us for
// full/half work => latency-serialized stage->drain->compute loop.
// Attn Ps uses XOR chunk swizzle (not +72 pad) so dbuf LDS = exactly 40KB
// (4 blocks/CU).  setprio(1) wraps attn MFMA clusters.  Causal q-blocks
// dispatched longest-first.
// All 128B LDS rows use the XOR chunk swizzle (chunk ^= row&7) applied on the
// GLOBAL fetch address so global_load_lds's lane-linear LDS dest still lands
// data where conflict-minimal ds_read_b128 fragment reads expect it.

#define S_LEN 2048
#define DMODEL 1024
#define NHEAD 16
#define DHEAD 64
#define HIDDEN 4096

using bf16 = __hip_bfloat16;
typedef __attribute__((ext_vector_type(8))) short bf16x8;
typedef __attribute__((ext_vector_type(4))) float floatx4;

__device__ __forceinline__ void async_ld16(const void* g, void* l) {
  __builtin_amdgcn_global_load_lds(
      (const __attribute__((address_space(1))) unsigned int*)g,
      (__attribute__((address_space(3))) unsigned int*)l, 16, 0, 0);
}

__device__ __forceinline__ unsigned short f2bf_bits(float f) {
  __hip_bfloat16 b = __float2bfloat16(f);
  return *(unsigned short*)&b;
}

// ---------------------------------------------------------------------------
// Transpose-convert weights: src fp32 (K x N, or head-blocked (H,K,64)) ->
// dst bf16 [N][K].  32x32 LDS tile, block 256 (32x8).  grid.z selects pair.
// ---------------------------------------------------------------------------
template <bool HEADB>
__global__ __launch_bounds__(256) void transp_bf16_kernel(
    const float* __restrict__ src0, bf16* __restrict__ dst0,
    const float* __restrict__ src1, bf16* __restrict__ dst1, int K, int N) {
  const float* src = blockIdx.z ? src1 : src0;
  bf16* dst = blockIdx.z ? dst1 : dst0;
  __shared__ float tile[32][33];
  const int tx = threadIdx.x & 31, ty = threadIdx.x >> 5;
  const int k0 = blockIdx.y * 32, n0 = blockIdx.x * 32;
#pragma unroll
  for (int i = 0; i < 4; ++i) {
    const int k = k0 + ty + i * 8;
    const int n = n0 + tx;
    size_t idx;
    if (HEADB)
      idx = (size_t)(n >> 6) * ((size_t)K * 64) + (size_t)k * 64 + (n & 63);
    else
      idx = (size_t)k * N + n;
    tile[ty + i * 8][tx] = src[idx];
  }
  __syncthreads();
#pragma unroll
  for (int i = 0; i < 4; ++i) {
    const int n = n0 + ty + i * 8;
    const int k = k0 + tx;
    dst[(size_t)n * K + k] = __float2bfloat16(tile[tx][ty + i * 8]);
  }
}

// straight fp32 -> bf16, 4 elements/thread; grid.z selects src/dst pair
__global__ __launch_bounds__(256) void conv_bf16_kernel(
    const float* __restrict__ src0, bf16* __restrict__ dst0,
    const float* __restrict__ src1, bf16* __restrict__ dst1, int n4) {
  const float* src = blockIdx.z ? src1 : src0;
  bf16* dst = blockIdx.z ? dst1 : dst0;
  const int i = blockIdx.x * 256 + threadIdx.x;
  if (i >= n4) return;
  float4 v = ((const float4*)src)[i];
  unsigned short r[4] = {f2bf_bits(v.x), f2bf_bits(v.y), f2bf_bits(v.z), f2bf_bits(v.w)};
  ((ushort2*)dst)[i * 2] = make_ushort2(r[0], r[1]);
  ((ushort2*)dst)[i * 2 + 1] = make_ushort2(r[2], r[3]);
}

// ---------------------------------------------------------------------------
// MFMA GEMM: C[M,N] = A[M,Klen] @ Bt[N,Klen]^T (+ bias[N]), optional ReLU.
// Rows strided by Kstride (split-K via pre-offset ptrs).  BK=64: LDS rows are
// 128B / 8 chunks, XOR-swizzled.  Double-buffered 2-phase pipeline: tile t+1
// staged (global_load_lds, no wait) before compute of tile t; one
// __syncthreads (vmcnt(0)+lgkmcnt(0) drain) per tile.
// BM,BN in {64,128}; 256 thr = 4 waves in 2x2.  DUALT: also emit C^T bf16.
// grid.z selects problem 0/1.
// ---------------------------------------------------------------------------
template <int BM, int BN, bool RELU, bool DUALT, typename CT>
__global__ __launch_bounds__(256) void mfma_gemm_kernel(
    const bf16* __restrict__ A0, const bf16* __restrict__ Bt0,
    const float* __restrict__ bias0, CT* __restrict__ C0,
    bf16* __restrict__ Ct0,
    const bf16* __restrict__ A1, const bf16* __restrict__ Bt1,
    const float* __restrict__ bias1, CT* __restrict__ C1,
    bf16* __restrict__ Ct1,
    int M, int N, int Kstride, int Klen) {
  const bf16* A = blockIdx.z ? A1 : A0;
  const bf16* Bt = blockIdx.z ? Bt1 : Bt0;
  const float* bias = blockIdx.z ? bias1 : bias0;
  CT* C = blockIdx.z ? C1 : C0;
  bf16* Ct = blockIdx.z ? Ct1 : Ct0;

  constexpr int MF = BM / 32;
  constexpr int NF = BN / 32;
  __shared__ __align__(16) bf16 As[2][BM * 64];
  __shared__ __align__(16) bf16 Bs[2][BN * 64];

  const int tid = threadIdx.x;
  const int wave = tid >> 6;
  const int lane = tid & 63;
  const int m0 = blockIdx.y * BM;
  const int n0 = blockIdx.x * BN;
  const int wr = wave >> 1, wc = wave & 1;

  // staging: thread -> row tid>>3 (32 rows / 4096B issue), swizzled chunk
  const int srow = tid >> 3;
  const int schunk = (tid & 7) ^ (srow & 7);
  const bf16* agp = A + (size_t)(m0 + srow) * Kstride + schunk * 8;
  const bf16* bgp = Bt + (size_t)(n0 + srow) * Kstride + schunk * 8;

  floatx4 acc[MF][NF];
#pragma unroll
  for (int i = 0; i < MF; ++i)
#pragma unroll
    for (int j = 0; j < NF; ++j) acc[i][j] = floatx4{0.f, 0.f, 0.f, 0.f};

  const int mrow = lane & 15;
  const int p0 = (((lane >> 4) ^ (mrow & 7)) << 4);  // swizzled chunk pos
  const int p1 = p0 ^ 64;                            // k-step 1 (chunk+4)

  auto stage = [&](int buf, int kt) {
    char* al = (char*)As + buf * (BM * 128) + wave * 1024;
    char* bl = (char*)Bs + buf * (BN * 128) + wave * 1024;
#pragma unroll
    for (int i = 0; i < BM / 32; ++i)
      async_ld16(agp + (size_t)(32 * i) * Kstride + kt, al + i * 4096);
#pragma unroll
    for (int i = 0; i < BN / 32; ++i)
      async_ld16(bgp + (size_t)(32 * i) * Kstride + kt, bl + i * 4096);
  };

  stage(0, 0);
  __syncthreads();  // drains vmcnt(0): buffer 0 ready

  int cur = 0;
  for (int kt = 0; kt < Klen; kt += 64) {
    if (kt + 64 < Klen) stage(cur ^ 1, kt + 64);  // prefetch, no wait

    const char* abase = (const char*)As + cur * (BM * 128);
    const char* bbase = (const char*)Bs + cur * (BN * 128);
    bf16x8 af0[MF], af1[MF], bf0[NF], bf1[NF];
#pragma unroll
    for (int fi = 0; fi < MF; ++fi) {
      const char* ar = abase + (wr * (BM / 2) + fi * 16 + mrow) * 128;
      af0[fi] = *(const bf16x8*)(ar + p0);
      af1[fi] = *(const bf16x8*)(ar + p1);
    }
#pragma unroll
    for (int fj = 0; fj < NF; ++fj) {
      const char* br = bbase + (wc * (BN / 2) + fj * 16 + mrow) * 128;
      bf0[fj] = *(const bf16x8*)(br + p0);
      bf1[fj] = *(const bf16x8*)(br + p1);
    }
#pragma unroll
    for (int fi = 0; fi < MF; ++fi)
#pragma unroll
      for (int fj = 0; fj < NF; ++fj) {
        acc[fi][fj] = __builtin_amdgcn_mfma_f32_16x16x32_bf16(
            af0[fi], bf0[fj], acc[fi][fj], 0, 0, 0);
        acc[fi][fj] = __builtin_amdgcn_mfma_f32_16x16x32_bf16(
            af1[fi], bf1[fj], acc[fi][fj], 0, 0, 0);
      }

    __syncthreads();  // next-tile loads landed; all reads of cur done
    cur ^= 1;
  }

  const int erow = (lane >> 4) * 4;
  const int ecol = lane & 15;
#pragma unroll
  for (int fi = 0; fi < MF; ++fi) {
#pragma unroll
    for (int fj = 0; fj < NF; ++fj) {
      const int nn = n0 + wc * (BN / 2) + fj * 16 + ecol;
      const float bv = bias ? bias[nn] : 0.0f;
      const int mmb = m0 + wr * (BM / 2) + fi * 16 + erow;
      float v[4];
#pragma unroll
      for (int r = 0; r < 4; ++r) {
        v[r] = acc[fi][fj][r] + bv;
        if (RELU) v[r] = fmaxf(v[r], 0.0f);
        if constexpr (sizeof(CT) == 2)
          C[(size_t)(mmb + r) * N + nn] = (CT)__float2bfloat16(v[r]);
        else
          C[(size_t)(mmb + r) * N + nn] = (CT)v[r];
      }
      if (DUALT) {
        ushort4 pk;
        pk.x = f2bf_bits(v[0]);
        pk.y = f2bf_bits(v[1]);
        pk.z = f2bf_bits(v[2]);
        pk.w = f2bf_bits(v[3]);
        *(ushort4*)&Ct[(size_t)nn * M + mmb] = pk;
      }
    }
  }
}

// ---------------------------------------------------------------------------
// MFMA flash attention, fixed-max softmax, split-K partials (k == v).
// Block = 128 thr = 2 waves per (64-q tile, head, k-parity z); wave owns 32 q
// as two 16-q subtiles -> 32 MFMA per staged K/V tile per wave, with
// K-frag and V-frag ds_reads shared across the two subtiles.
// Double-buffered 2-phase pipeline (stage t+1 before compute t, single
// __syncthreads per tile).  Ps is [32][64] per wave with a 16B XOR chunk
// swizzle ((q&7)<<4) instead of +72 padding: total LDS = 16+16+8 = 40KB
// exactly -> 4 blocks/CU.
// S^T = K.Q^T (C-layout: 4 consecutive t per lane at fixed q) -> P stores are
// ds_write_b64, l-reduce is 2 shuffles.  PV: O^T = V^T @ P^T.
// Emits UNNORMALIZED O-partial + l-partial; consuming LN merges.
// Causal blocks are dispatched longest-first (qb reversed).
// ---------------------------------------------------------------------------
__global__ __launch_bounds__(128) void mfma_attn_kernel(
    const bf16* __restrict__ Q, const bf16* __restrict__ K,
    const bf16* __restrict__ Vt,
    float* __restrict__ OA, float* __restrict__ OB,
    float* __restrict__ LA, float* __restrict__ LB, int causal) {
  __shared__ __align__(16) unsigned short Kt[2][64 * 64];  // [t][d] swizzled
  __shared__ __align__(16) unsigned short Vs[2][64 * 64];  // [d][t] swizzled
  __shared__ __align__(16) unsigned short Ps[2][2048];     // per-wave P, swz

  const int tid = threadIdx.x;
  const int w = tid >> 6, lane = tid & 63;
  const int g = lane >> 4, c = lane & 15;
  const int h = blockIdx.y;
  const int qb = causal ? ((int)gridDim.x - 1 - (int)blockIdx.x)
                        : (int)blockIdx.x;
  const int q0 = qb * 64;
  const int z = blockIdx.z;
  const int qw = q0 + w * 32;
  float* Oz = z ? OB : OA;
  float* Lz = z ? LB : LA;

  // Q B-frags for the wave's two 16-q subtiles
  bf16x8 qf0[2], qf1[2];
#pragma unroll
  for (int qs = 0; qs < 2; ++qs) {
    const bf16* qrow =
        Q + (size_t)(qw + qs * 16 + c) * DMODEL + h * DHEAD + g * 8;
    qf0[qs] = *(const bf16x8*)qrow;
    qf1[qs] = *(const bf16x8*)(qrow + 32);
  }

  // staging: thread -> tile row tid>>3 (16 rows / 2048B issue), swizzled chunk
  const int srow = tid >> 3;                 // 0..15
  const int schunk = (tid & 7) ^ (srow & 7);
  const bf16* kgp = K + (size_t)srow * DMODEL + h * DHEAD + schunk * 8;
  const bf16* vgp = Vt + (size_t)(h * DHEAD + srow) * S_LEN + schunk * 8;

  const int kpos0 = ((g ^ (c & 7)) << 4);
  const int kpos1 = kpos0 ^ 64;

  floatx4 of[4][2];
#pragma unroll
  for (int md = 0; md < 4; ++md)
#pragma unroll
    for (int qs = 0; qs < 2; ++qs) of[md][qs] = floatx4{0.f, 0.f, 0.f, 0.f};
  float lpart[2] = {0.f, 0.f};

  const int nkt = causal ? (q0 / 64 + 1) : (S_LEN / 64);

  auto stage = [&](int buf, int kt) {
    const int t0 = kt * 64;
    char* klds = (char*)Kt + buf * 8192 + w * 1024;
    char* vlds = (char*)Vs + buf * 8192 + w * 1024;
#pragma unroll
    for (int i = 0; i < 4; ++i) {
      async_ld16(kgp + (size_t)(t0 + 16 * i) * DMODEL, klds + i * 2048);
      async_ld16(vgp + (size_t)(16 * i) * S_LEN + t0, vlds + i * 2048);
    }
  };

  if (z < nkt) stage(0, z);
  __syncthreads();  // buffer 0 ready

  int cur = 0;
  for (int kt = z; kt < nkt; kt += 2) {
    const int t0 = kt * 64;
    if (kt + 2 < nkt) stage(cur ^ 1, kt + 2);  // prefetch next, no wait

    const char* kbase = (const char*)Kt + cur * 8192;
    const char* vbase = (const char*)Vs + cur * 8192;

    // --- S^T = K Q^T : rows t (4/lane), col q=c; two q-subtiles ---
    const bool diag = causal && (t0 == q0);
#pragma unroll
    for (int jt = 0; jt < 4; ++jt) {
      const char* kr = kbase + (16 * jt + c) * 128;
      const bf16x8 kf0 = *(const bf16x8*)(kr + kpos0);
      const bf16x8 kf1 = *(const bf16x8*)(kr + kpos1);
#pragma unroll
      for (int qs = 0; qs < 2; ++qs) {
        floatx4 s = floatx4{0.f, 0.f, 0.f, 0.f};
        __builtin_amdgcn_s_setprio(1);
        s = __builtin_amdgcn_mfma_f32_16x16x32_bf16(kf0, qf0[qs], s, 0, 0, 0);
        s = __builtin_amdgcn_mfma_f32_16x16x32_bf16(kf1, qf1[qs], s, 0, 0, 0);
        __builtin_amdgcn_s_setprio(0);

        ushort4 pk;
        unsigned short* pp = (unsigned short*)&pk;
#pragma unroll
        for (int r = 0; r < 4; ++r) {
          float p = __expf(0.125f * s[r]);
          if (diag && (t0 + 16 * jt + 4 * g + r > qw + qs * 16 + c)) p = 0.0f;
          lpart[qs] += p;
          pp[r] = f2bf_bits(p);
        }
        const int qq = qs * 16 + c;
        const int pb = qq * 128 + ((8 * (4 * jt + g)) ^ ((qq & 7) << 4));
        *(ushort4*)((char*)Ps[w] + pb) = pk;
      }
    }

    // --- O^T += V^T @ P^T (V-frags shared across q-subtiles) ---
#pragma unroll
    for (int ks = 0; ks < 2; ++ks) {
      const int px = (64 * ks + 16 * g) ^ ((c & 7) << 4);
      const bf16x8 pf0 = *(const bf16x8*)((const char*)Ps[w] + c * 128 + px);
      const bf16x8 pf1 =
          *(const bf16x8*)((const char*)Ps[w] + (16 + c) * 128 + px);
      const int vpos = ks ? kpos1 : kpos0;
#pragma unroll
      for (int md = 0; md < 4; ++md) {
        const bf16x8 vf = *(const bf16x8*)(vbase + (md * 16 + c) * 128 + vpos);
        __builtin_amdgcn_s_setprio(1);
        of[md][0] = __builtin_amdgcn_mfma_f32_16x16x32_bf16(vf, pf0, of[md][0], 0, 0, 0);
        of[md][1] = __builtin_amdgcn_mfma_f32_16x16x32_bf16(vf, pf1, of[md][1], 0, 0, 0);
        __builtin_amdgcn_s_setprio(0);
      }
    }

    __syncthreads();  // next-tile loads landed; all reads of cur done
    cur ^= 1;
  }

  // --- l reduce (over g-groups) + unnormalized O-partial write ---
#pragma unroll
  for (int qs = 0; qs < 2; ++qs) {
    lpart[qs] += __shfl_xor(lpart[qs], 16, 64);
    lpart[qs] += __shfl_xor(lpart[qs], 32, 64);
    if (g == 0) Lz[(size_t)h * S_LEN + qw + qs * 16 + c] = lpart[qs];
    float* orow = Oz + (size_t)(qw + qs * 16 + c) * DMODEL + h * DHEAD;
#pragma unroll
    for (int md = 0; md < 4; ++md) {
      float4 v;
      v.x = of[md][qs][0];
      v.y = of[md][qs][1];
      v.z = of[md][qs][2];
      v.w = of[md][qs][3];
      *(float4*)(orow + md * 16 + 4 * g) = v;
    }
  }
}

// ---------------------------------------------------------------------------
// LayerNorm variants.  One block (256 thr) per row, D=1024.
// MERGE: x = X + (R+R2) / (La[h][row]+Lb[h][row])   (attention partial merge)
// SUM2 : x = X + R + R2 + bvec                      (split-K FFN + bias)
// else : x = X + R
// ---------------------------------------------------------------------------
template <bool DUAL, bool MERGE, bool SUM2>
__global__ __launch_bounds__(256) void add_ln_kernel(
    const float* __restrict__ X, const float* __restrict__ R,
    const float* __restrict__ R2, const float* __restrict__ bvec,
    const float* __restrict__ La, const float* __restrict__ Lb,
    const float* __restrict__ g, const float* __restrict__ beta,
    float* __restrict__ out, bf16* __restrict__ out2) {
  const int row = blockIdx.x;
  const int tid = threadIdx.x;

  float v[4];
  float s1 = 0.0f, s2 = 0.0f;
#pragma unroll
  for (int i = 0; i < 4; ++i) {
    const int c = tid + i * 256;
    float x = X[(size_t)row * DMODEL + c];
    if (MERGE) {
      const int h = c >> 6;
      const float rl =
          1.0f / (La[(size_t)h * S_LEN + row] + Lb[(size_t)h * S_LEN + row]);
      x += (R[(size_t)row * DMODEL + c] + R2[(size_t)row * DMODEL + c]) * rl;
    } else if (SUM2) {
      x += R[(size_t)row * DMODEL + c] + R2[(size_t)row * DMODEL + c] + bvec[c];
    } else {
      x += R[(size_t)row * DMODEL + c];
    }
    v[i] = x;
    s1 += x;
    s2 += x * x;
  }
#pragma unroll
  for (int off = 32; off; off >>= 1) {
    s1 += __shfl_xor(s1, off, 64);
    s2 += __shfl_xor(s2, off, 64);
  }
  __shared__ float w1s[4], w2s[4];
  const int wid = tid >> 6, lane = tid & 63;
  if (lane == 0) { w1s[wid] = s1; w2s[wid] = s2; }
  __syncthreads();
  s1 = w1s[0] + w1s[1] + w1s[2] + w1s[3];
  s2 = w2s[0] + w2s[1] + w2s[2] + w2s[3];

  const float mu = s1 * (1.0f / DMODEL);
  const float var = s2 * (1.0f / DMODEL) - mu * mu;
  const float rstd = rsqrtf(var + 1e-5f);

#pragma unroll
  for (int i = 0; i < 4; ++i) {
    const int c = tid + i * 256;
    const float r = (v[i] - mu) * rstd * g[c] + beta[c];
    out[(size_t)row * DMODEL + c] = r;
    if (DUAL) out2[(size_t)row * DMODEL + c] = __float2bfloat16(r);
  }
}

// ---------------------------------------------------------------------------
extern "C" void kernel_launch(void* const* d_in, const int* in_sizes, int n_in,
                              void* d_out, int out_size, void* d_ws, size_t ws_size,
                              hipStream_t stream) {
  const float* y      = (const float*)d_in[0];
  const float* enc    = (const float*)d_in[1];
  const float* Wself  = (const float*)d_in[2];
  const float* bself  = (const float*)d_in[3];
  const float* Wcross = (const float*)d_in[4];
  const float* bcross = (const float*)d_in[5];
  const float* g1     = (const float*)d_in[6];
  const float* be1    = (const float*)d_in[7];
  const float* g2     = (const float*)d_in[8];
  const float* be2    = (const float*)d_in[9];
  const float* g3     = (const float*)d_in[10];
  const float* be3    = (const float*)d_in[11];
  const float* w1     = (const float*)d_in[12];
  const float* b1     = (const float*)d_in[13];
  const float* w2     = (const float*)d_in[14];
  const float* b2     = (const float*)d_in[15];
  float* out = (float*)d_out;

  char* ws = (char*)d_ws;
  const size_t MB = 1024 * 1024;
  bf16*  ybf   = (bf16*)(ws + 0 * MB);
  bf16*  encbf = (bf16*)(ws + 4 * MB);
  float* PA    = (float*)(ws + 0 * MB);
  float* PB    = (float*)(ws + 8 * MB);
  float* Y1    = (float*)(ws + 16 * MB);
  float* Y2    = (float*)(ws + 24 * MB);
  bf16*  Q12b  = (bf16*)(ws + 32 * MB);
  bf16*  Q1t   = (bf16*)(ws + 36 * MB);
  bf16*  K2b   = (bf16*)(ws + 40 * MB);
  bf16*  K2t   = (bf16*)(ws + 44 * MB);
  bf16*  w1t   = (bf16*)(ws + 48 * MB);
  bf16*  w2t   = (bf16*)(ws + 56 * MB);
  bf16*  Wst   = (bf16*)(ws + 64 * MB);
  bf16*  Wct   = (bf16*)(ws + 66 * MB);
  bf16*  Y1bf  = (bf16*)(ws + 68 * MB);
  bf16*  Y2bf  = (bf16*)(ws + 72 * MB);
  float* La    = (float*)(ws + 76 * MB);
  float* Lb    = (float*)(ws + 76 * MB + 512 * 1024);
  bf16*  FFH   = (bf16*)(ws + 0 * MB);    // 16 MB, overlays dead PA+PB
  float* FFa   = (float*)(ws + 32 * MB);  // overlays dead Q12b+Q1t
  float* FFb   = (float*)(ws + 40 * MB);  // overlays dead K2b+K2t

  const dim3 blk(256);
  const dim3 blkA(128);
  const dim3 gT_w(DMODEL / 32, DMODEL / 32, 2);
  const dim3 gT_w1(HIDDEN / 32, DMODEL / 32);
  const dim3 gT_w2(DMODEL / 32, HIDDEN / 32);
  const dim3 gConv(S_LEN * DMODEL / 4 / 256, 1, 2);
  const dim3 gProj2(DMODEL / 64, S_LEN / 64, 2);   // 1024 blocks
  const dim3 gProj(DMODEL / 64, S_LEN / 64);       // 512
  const dim3 gFf1(HIDDEN / 128, S_LEN / 64);       // 1024
  const dim3 gFf2(DMODEL / 64, S_LEN / 64, 2);     // 1024 (split-K)
  const dim3 gAttn(S_LEN / 64, NHEAD, 2);          // 1024 x 128thr (split-K)
  const dim3 gLn(S_LEN);

  // --- conversions ---
  transp_bf16_kernel<true><<<gT_w, blk, 0, stream>>>(
      Wself, Wst, Wcross, Wct, DMODEL, DMODEL);
  transp_bf16_kernel<false><<<gT_w1, blk, 0, stream>>>(
      w1, w1t, nullptr, nullptr, DMODEL, HIDDEN);
  transp_bf16_kernel<false><<<gT_w2, blk, 0, stream>>>(
      w2, w2t, nullptr, nullptr, HIDDEN, DMODEL);
  conv_bf16_kernel<<<gConv, blk, 0, stream>>>(
      y, ybf, enc, encbf, S_LEN * DMODEL / 4);

  // 1+4) Q1 = y@Wself+bself ; K2 = enc@Wcross+bcross  (dual C+C^T, one launch)
  mfma_gemm_kernel<64, 64, false, true, bf16><<<gProj2, blk, 0, stream>>>(
      ybf, Wst, bself, Q12b, Q1t,
      encbf, Wct, bcross, K2b, K2t, S_LEN, DMODEL, DMODEL, DMODEL);
  // 2) self-attention (causal), k=v=Q1; unnormalized partials
  mfma_attn_kernel<<<gAttn, blkA, 0, stream>>>(
      Q12b, Q12b, Q1t, PA, PB, La, Lb, 1);
  // 3) y1 = LN(y + (PA+PB)/(La+Lb))  (+ bf16 copy)
  add_ln_kernel<true, true, false><<<gLn, blk, 0, stream>>>(
      y, PA, PB, nullptr, La, Lb, g1, be1, Y1, Y1bf);
  // 5) Q2 = y1 @ Wcross + bcross
  mfma_gemm_kernel<64, 64, false, false, bf16><<<gProj, blk, 0, stream>>>(
      Y1bf, Wct, bcross, Q12b, nullptr,
      nullptr, nullptr, nullptr, nullptr, nullptr, S_LEN, DMODEL, DMODEL, DMODEL);
  // 6) cross-attention (full), k=v=K2
  mfma_attn_kernel<<<gAttn, blkA, 0, stream>>>(
      Q12b, K2b, K2t, PA, PB, La, Lb, 0);
  // 7) y2 = LN(y1 + (PA+PB)/(La+Lb))  (+ bf16 copy)
  add_ln_kernel<true, true, false><<<gLn, blk, 0, stream>>>(
      Y1, PA, PB, nullptr, La, Lb, g2, be2, Y2, Y2bf);
  // 8) ffh = relu(y2 @ w1 + b1) -> bf16
  mfma_gemm_kernel<64, 128, true, false, bf16><<<gFf1, blk, 0, stream>>>(
      Y2bf, w1t, b1, FFH, nullptr,
      nullptr, nullptr, nullptr, nullptr, nullptr, S_LEN, HIDDEN, DMODEL, DMODEL);
  // 9) split-K FFN2
  mfma_gemm_kernel<64, 64, false, false, float><<<gFf2, blk, 0, stream>>>(
      FFH, w2t, nullptr, FFa, nullptr,
      FFH + HIDDEN / 2, w2t + HIDDEN / 2, nullptr, FFb, nullptr,
      S_LEN, DMODEL, HIDDEN, HIDDEN / 2);
  // 10) out = LN(y2 + FFa + FFb + b2)
  add_ln_kernel<false, false, true><<<gLn, blk, 0, stream>>>(
      Y2, FFa, FFb, b2, nullptr, nullptr, g3, be3, out, nullptr);
}

// Round 3
// 306.630 us; speedup vs baseline: 1.0250x; 1.0234x over previous
//
#include <hip/hip_runtime.h>
#include <hip/hip_bf16.h>

// Decoder layer: self-attn (causal, shared qkv proj) + LN, cross-attn + LN,
// FFN (relu) + LN.  B=1, S=2048, D=1024, H=16, DH=64, HID=4096.
// I/O fp32.  GEMMs + attention bf16 MFMA (16x16x32), fp32 accumulate.
// Fixed-max softmax => split-K attention emits unnormalized O + l partials;
// the next LN merges.
// R13: attn re-tiled for TLP *and* ILP.  R12 counters: dbuf pipeline was
// neutral because LDS 25.6->40KB cut blocks/CU 6->4 (pipeline gain ==
// occupancy loss; causal==cross time => per-block latency-serialized).
// New attn: 256 thr = 4 waves x 16 q over a 64-q block, KV tile = 32 t,
// K/V double-buffered, LDS = 8+8+4 = 20KB -> 16 waves/CU (2x TLP) with the
// 2-phase pipeline kept.  ds_reads hoisted before the prefetch issue.
// Causal waves skip fully-masked tiles.  GEMM: FF1 64x128->64x64 (3->5
// resident blocks/CU), proj 64x64->32x64 (8->16 waves/CU).
// 128B LDS rows use chunk ^= row&7 swizzle; 64B rows (V,P) use
// chunk ^= (row>>1)&3 -- both applied on the GLOBAL fetch address so
// global_load_lds's lane-linear dest lands data where conflict-minimal
// ds_read_b128 fragment reads expect it.

#define S_LEN 2048
#define DMODEL 1024
#define NHEAD 16
#define DHEAD 64
#define HIDDEN 4096

using bf16 = __hip_bfloat16;
typedef __attribute__((ext_vector_type(8))) short bf16x8;
typedef __attribute__((ext_vector_type(4))) float floatx4;

__device__ __forceinline__ void async_ld16(const void* g, void* l) {
  __builtin_amdgcn_global_load_lds(
      (const __attribute__((address_space(1))) unsigned int*)g,
      (__attribute__((address_space(3))) unsigned int*)l, 16, 0, 0);
}

__device__ __forceinline__ unsigned short f2bf_bits(float f) {
  __hip_bfloat16 b = __float2bfloat16(f);
  return *(unsigned short*)&b;
}

// ---------------------------------------------------------------------------
// Transpose-convert weights: src fp32 (K x N, or head-blocked (H,K,64)) ->
// dst bf16 [N][K].  32x32 LDS tile, block 256 (32x8).  grid.z selects pair.
// ---------------------------------------------------------------------------
template <bool HEADB>
__global__ __launch_bounds__(256) void transp_bf16_kernel(
    const float* __restrict__ src0, bf16* __restrict__ dst0,
    const float* __restrict__ src1, bf16* __restrict__ dst1, int K, int N) {
  const float* src = blockIdx.z ? src1 : src0;
  bf16* dst = blockIdx.z ? dst1 : dst0;
  __shared__ float tile[32][33];
  const int tx = threadIdx.x & 31, ty = threadIdx.x >> 5;
  const int k0 = blockIdx.y * 32, n0 = blockIdx.x * 32;
#pragma unroll
  for (int i = 0; i < 4; ++i) {
    const int k = k0 + ty + i * 8;
    const int n = n0 + tx;
    size_t idx;
    if (HEADB)
      idx = (size_t)(n >> 6) * ((size_t)K * 64) + (size_t)k * 64 + (n & 63);
    else
      idx = (size_t)k * N + n;
    tile[ty + i * 8][tx] = src[idx];
  }
  __syncthreads();
#pragma unroll
  for (int i = 0; i < 4; ++i) {
    const int n = n0 + ty + i * 8;
    const int k = k0 + tx;
    dst[(size_t)n * K + k] = __float2bfloat16(tile[tx][ty + i * 8]);
  }
}

// straight fp32 -> bf16, 4 elements/thread; grid.z selects src/dst pair
__global__ __launch_bounds__(256) void conv_bf16_kernel(
    const float* __restrict__ src0, bf16* __restrict__ dst0,
    const float* __restrict__ src1, bf16* __restrict__ dst1, int n4) {
  const float* src = blockIdx.z ? src1 : src0;
  bf16* dst = blockIdx.z ? dst1 : dst0;
  const int i = blockIdx.x * 256 + threadIdx.x;
  if (i >= n4) return;
  float4 v = ((const float4*)src)[i];
  unsigned short r[4] = {f2bf_bits(v.x), f2bf_bits(v.y), f2bf_bits(v.z), f2bf_bits(v.w)};
  ((ushort2*)dst)[i * 2] = make_ushort2(r[0], r[1]);
  ((ushort2*)dst)[i * 2 + 1] = make_ushort2(r[2], r[3]);
}

// ---------------------------------------------------------------------------
// MFMA GEMM: C[M,N] = A[M,Klen] @ Bt[N,Klen]^T (+ bias[N]), optional ReLU.
// Rows strided by Kstride (split-K via pre-offset ptrs).  BK=64: LDS rows are
// 128B / 8 chunks, XOR-swizzled.  Double-buffered 2-phase pipeline: ds_reads
// of tile t first, then stage(t+1) (global_load_lds, no wait), then MFMA;
// one __syncthreads per tile.
// BM in {32,64,128}, BN in {64,128}; 256 thr = 4 waves in 2x2.
// DUALT: also emit C^T bf16.  grid.z selects problem 0/1.
// ---------------------------------------------------------------------------
template <int BM, int BN, bool RELU, bool DUALT, typename CT>
__global__ __launch_bounds__(256) void mfma_gemm_kernel(
    const bf16* __restrict__ A0, const bf16* __restrict__ Bt0,
    const float* __restrict__ bias0, CT* __restrict__ C0,
    bf16* __restrict__ Ct0,
    const bf16* __restrict__ A1, const bf16* __restrict__ Bt1,
    const float* __restrict__ bias1, CT* __restrict__ C1,
    bf16* __restrict__ Ct1,
    int M, int N, int Kstride, int Klen) {
  const bf16* A = blockIdx.z ? A1 : A0;
  const bf16* Bt = blockIdx.z ? Bt1 : Bt0;
  const float* bias = blockIdx.z ? bias1 : bias0;
  CT* C = blockIdx.z ? C1 : C0;
  bf16* Ct = blockIdx.z ? Ct1 : Ct0;

  constexpr int MF = (BM + 31) / 32;
  constexpr int NF = BN / 32;
  __shared__ __align__(16) bf16 As[2][BM * 64];
  __shared__ __align__(16) bf16 Bs[2][BN * 64];

  const int tid = threadIdx.x;
  const int wave = tid >> 6;
  const int lane = tid & 63;
  const int m0 = blockIdx.y * BM;
  const int n0 = blockIdx.x * BN;
  const int wr = wave >> 1, wc = wave & 1;

  // staging: thread -> row tid>>3 (32 rows / 4096B issue), swizzled chunk
  const int srow = tid >> 3;
  const int schunk = (tid & 7) ^ (srow & 7);
  const bf16* agp = A + (size_t)(m0 + srow) * Kstride + schunk * 8;
  const bf16* bgp = Bt + (size_t)(n0 + srow) * Kstride + schunk * 8;

  floatx4 acc[MF][NF];
#pragma unroll
  for (int i = 0; i < MF; ++i)
#pragma unroll
    for (int j = 0; j < NF; ++j) acc[i][j] = floatx4{0.f, 0.f, 0.f, 0.f};

  const int mrow = lane & 15;
  const int p0 = (((lane >> 4) ^ (mrow & 7)) << 4);  // swizzled chunk pos
  const int p1 = p0 ^ 64;                            // k-step 1 (chunk+4)

  auto stage = [&](int buf, int kt) {
    char* al = (char*)As + buf * (BM * 128) + wave * 1024;
    char* bl = (char*)Bs + buf * (BN * 128) + wave * 1024;
#pragma unroll
    for (int i = 0; i < BM / 32; ++i)
      async_ld16(agp + (size_t)(32 * i) * Kstride + kt, al + i * 4096);
#pragma unroll
    for (int i = 0; i < BN / 32; ++i)
      async_ld16(bgp + (size_t)(32 * i) * Kstride + kt, bl + i * 4096);
  };

  stage(0, 0);
  __syncthreads();  // drains vmcnt(0): buffer 0 ready

  int cur = 0;
  for (int kt = 0; kt < Klen; kt += 64) {
    const char* abase = (const char*)As + cur * (BM * 128);
    const char* bbase = (const char*)Bs + cur * (BN * 128);
    bf16x8 af0[MF], af1[MF], bf0[NF], bf1[NF];
#pragma unroll
    for (int fi = 0; fi < MF; ++fi) {
      const char* ar = abase + (wr * (BM / 2) + fi * 16 + mrow) * 128;
      af0[fi] = *(const bf16x8*)(ar + p0);
      af1[fi] = *(const bf16x8*)(ar + p1);
    }
#pragma unroll
    for (int fj = 0; fj < NF; ++fj) {
      const char* br = bbase + (wc * (BN / 2) + fj * 16 + mrow) * 128;
      bf0[fj] = *(const bf16x8*)(br + p0);
      bf1[fj] = *(const bf16x8*)(br + p1);
    }

    if (kt + 64 < Klen) stage(cur ^ 1, kt + 64);  // prefetch, no wait

#pragma unroll
    for (int fi = 0; fi < MF; ++fi)
#pragma unroll
      for (int fj = 0; fj < NF; ++fj) {
        acc[fi][fj] = __builtin_amdgcn_mfma_f32_16x16x32_bf16(
            af0[fi], bf0[fj], acc[fi][fj], 0, 0, 0);
        acc[fi][fj] = __builtin_amdgcn_mfma_f32_16x16x32_bf16(
            af1[fi], bf1[fj], acc[fi][fj], 0, 0, 0);
      }

    __syncthreads();  // next-tile loads landed; all reads of cur done
    cur ^= 1;
  }

  const int erow = (lane >> 4) * 4;
  const int ecol = lane & 15;
#pragma unroll
  for (int fi = 0; fi < MF; ++fi) {
#pragma unroll
    for (int fj = 0; fj < NF; ++fj) {
      const int nn = n0 + wc * (BN / 2) + fj * 16 + ecol;
      const float bv = bias ? bias[nn] : 0.0f;
      const int mmb = m0 + wr * (BM / 2) + fi * 16 + erow;
      float v[4];
#pragma unroll
      for (int r = 0; r < 4; ++r) {
        v[r] = acc[fi][fj][r] + bv;
        if (RELU) v[r] = fmaxf(v[r], 0.0f);
        if constexpr (sizeof(CT) == 2)
          C[(size_t)(mmb + r) * N + nn] = (CT)__float2bfloat16(v[r]);
        else
          C[(size_t)(mmb + r) * N + nn] = (CT)v[r];
      }
      if (DUALT) {
        ushort4 pk;
        pk.x = f2bf_bits(v[0]);
        pk.y = f2bf_bits(v[1]);
        pk.z = f2bf_bits(v[2]);
        pk.w = f2bf_bits(v[3]);
        *(ushort4*)&Ct[(size_t)nn * M + mmb] = pk;
      }
    }
  }
}

// ---------------------------------------------------------------------------
// MFMA flash attention, fixed-max softmax, split-K partials (k == v).
// Block = 256 thr = 4 waves per (64-q tile, head, k-parity z); wave owns 16 q.
// KV tile = 32 t.  K/V double-buffered (2-phase: ds_reads -> stage(t+1) ->
// compute -> one __syncthreads).  LDS = Kt 2x4KB + Vs 2x4KB + Ps 4x1KB = 20KB
// -> 4 blocks/CU x 4 waves = 16 waves/CU.
// Kt rows 128B (chunk ^= row&7); Vs/Ps rows 64B (chunk ^= (row>>1)&3), both
// pre-applied on the global fetch address (lane-linear LDS dest).
// S^T = K.Q^T (C: 4 consecutive t per lane at fixed q) -> P stores are
// ds_write_b64, l-reduce is 2 shuffles.  PV: O^T = V^T @ P^T, k=32 in one
// MFMA per (d-block).  Emits UNNORMALIZED O-partial + l-partial; LN merges.
// Causal q-blocks dispatched longest-first; waves skip fully-masked tiles.
// ---------------------------------------------------------------------------
__global__ __launch_bounds__(256) void mfma_attn_kernel(
    const bf16* __restrict__ Q, const bf16* __restrict__ K,
    const bf16* __restrict__ Vt,
    float* __restrict__ OA, float* __restrict__ OB,
    float* __restrict__ LA, float* __restrict__ LB, int causal) {
  __shared__ __align__(16) unsigned short Kt[2][32 * 64];  // [t][d] swizzled
  __shared__ __align__(16) unsigned short Vs[2][64 * 32];  // [d][t] swizzled
  __shared__ __align__(16) unsigned short Ps[4][512];      // per-wave P [q][t]

  const int tid = threadIdx.x;
  const int w = tid >> 6, lane = tid & 63;
  const int g = lane >> 4, c = lane & 15;
  const int h = blockIdx.y;
  const int qb = causal ? ((int)gridDim.x - 1 - (int)blockIdx.x)
                        : (int)blockIdx.x;
  const int q0 = qb * 64;
  const int z = blockIdx.z;
  const int qw = q0 + w * 16;  // this wave's 16-q subtile
  float* Oz = z ? OB : OA;
  float* Lz = z ? LB : LA;

  // Q B-frags for the wave's 16-q subtile (d halves 0..31 / 32..63)
  const bf16* qrow = Q + (size_t)(qw + c) * DMODEL + h * DHEAD + g * 8;
  const bf16x8 qfa = *(const bf16x8*)qrow;
  const bf16x8 qfb = *(const bf16x8*)(qrow + 32);

  // staging addresses (global pre-swizzled, LDS dest lane-linear)
  const int srk = tid >> 3;                        // K row 0..31 (128B rows)
  const int sck = (tid & 7) ^ (srk & 7);
  const bf16* kgp = K + (size_t)srk * DMODEL + h * DHEAD + sck * 8;
  const int srv = tid >> 2;                        // V row 0..63 (64B rows)
  const int scv = (tid & 3) ^ ((srv >> 1) & 3);
  const bf16* vgp = Vt + (size_t)(h * DHEAD + srv) * S_LEN + scv * 8;

  const int kpos0 = ((g ^ (c & 7)) << 4);
  const int kpos1 = kpos0 ^ 64;
  const int vpos = ((g ^ ((c >> 1) & 3)) << 4);    // also the P-read pos
  char* pswave = (char*)Ps + w * 1024;

  floatx4 of[4];
#pragma unroll
  for (int md = 0; md < 4; ++md) of[md] = floatx4{0.f, 0.f, 0.f, 0.f};
  float lpart = 0.f;

  const int nkt = causal ? (q0 / 32 + 2) : (S_LEN / 32);

  auto stage = [&](int buf, int kt) {
    const int t0 = kt * 32;
    async_ld16(kgp + (size_t)t0 * DMODEL, (char*)Kt + buf * 4096 + w * 1024);
    async_ld16(vgp + t0, (char*)Vs + buf * 4096 + w * 1024);
  };

  stage(0, z);
  __syncthreads();  // buffer 0 ready

  int cur = 0;
  for (int kt = z; kt < nkt; kt += 2) {
    const int t0 = kt * 32;
    const bool act = !(causal && t0 >= qw + 16);  // wave-uniform

    bf16x8 kf00, kf01, kf10, kf11, vf0, vf1, vf2, vf3;
    if (act) {
      const char* kbase = (const char*)Kt + cur * 4096;
      const char* vbase = (const char*)Vs + cur * 4096;
      const char* kr0 = kbase + c * 128;
      const char* kr1 = kbase + (16 + c) * 128;
      kf00 = *(const bf16x8*)(kr0 + kpos0);
      kf01 = *(const bf16x8*)(kr0 + kpos1);
      kf10 = *(const bf16x8*)(kr1 + kpos0);
      kf11 = *(const bf16x8*)(kr1 + kpos1);
      vf0 = *(const bf16x8*)(vbase + (c)*64 + vpos);
      vf1 = *(const bf16x8*)(vbase + (16 + c) * 64 + vpos);
      vf2 = *(const bf16x8*)(vbase + (32 + c) * 64 + vpos);
      vf3 = *(const bf16x8*)(vbase + (48 + c) * 64 + vpos);
    }

    if (kt + 2 < nkt) stage(cur ^ 1, kt + 2);  // prefetch next, no wait

    if (act) {
      const bool diag = causal && (t0 + 32 > qw);
      // --- S^T = K Q^T : rows t (4/lane), col q = c ---
#pragma unroll
      for (int jt = 0; jt < 2; ++jt) {
        floatx4 s = floatx4{0.f, 0.f, 0.f, 0.f};
        __builtin_amdgcn_s_setprio(1);
        s = __builtin_amdgcn_mfma_f32_16x16x32_bf16(jt ? kf10 : kf00, qfa, s, 0, 0, 0);
        s = __builtin_amdgcn_mfma_f32_16x16x32_bf16(jt ? kf11 : kf01, qfb, s, 0, 0, 0);
        __builtin_amdgcn_s_setprio(0);

        ushort4 pk;
        unsigned short* pp = (unsigned short*)&pk;
#pragma unroll
        for (int r = 0; r < 4; ++r) {
          float p = __expf(0.125f * s[r]);
          if (diag && (t0 + 16 * jt + 4 * g + r > qw + c)) p = 0.0f;
          lpart += p;
          pp[r] = f2bf_bits(p);
        }
        const int pb =
            c * 64 + ((((2 * jt + (g >> 1)) ^ ((c >> 1) & 3)) << 4) |
                      ((g & 1) << 3));
        *(ushort4*)(pswave + pb) = pk;
      }

      // --- O^T += V^T @ P^T (k = 32 in one MFMA per d-block) ---
      const bf16x8 pf = *(const bf16x8*)(pswave + c * 64 + vpos);
      __builtin_amdgcn_s_setprio(1);
      of[0] = __builtin_amdgcn_mfma_f32_16x16x32_bf16(vf0, pf, of[0], 0, 0, 0);
      of[1] = __builtin_amdgcn_mfma_f32_16x16x32_bf16(vf1, pf, of[1], 0, 0, 0);
      of[2] = __builtin_amdgcn_mfma_f32_16x16x32_bf16(vf2, pf, of[2], 0, 0, 0);
      of[3] = __builtin_amdgcn_mfma_f32_16x16x32_bf16(vf3, pf, of[3], 0, 0, 0);
      __builtin_amdgcn_s_setprio(0);
    }

    __syncthreads();  // next-tile loads landed; all reads of cur done
    cur ^= 1;
  }

  // --- l reduce (over g-groups) + unnormalized O-partial write ---
  lpart += __shfl_xor(lpart, 16, 64);
  lpart += __shfl_xor(lpart, 32, 64);
  if (g == 0) Lz[(size_t)h * S_LEN + qw + c] = lpart;
  float* orow = Oz + (size_t)(qw + c) * DMODEL + h * DHEAD;
#pragma unroll
  for (int md = 0; md < 4; ++md) {
    float4 v;
    v.x = of[md][0];
    v.y = of[md][1];
    v.z = of[md][2];
    v.w = of[md][3];
    *(float4*)(orow + md * 16 + 4 * g) = v;
  }
}

// ---------------------------------------------------------------------------
// LayerNorm variants.  One block (256 thr) per row, D=1024.
// MERGE: x = X + (R+R2) / (La[h][row]+Lb[h][row])   (attention partial merge)
// SUM2 : x = X + R + R2 + bvec                      (split-K FFN + bias)
// else : x = X + R
// ---------------------------------------------------------------------------
template <bool DUAL, bool MERGE, bool SUM2>
__global__ __launch_bounds__(256) void add_ln_kernel(
    const float* __restrict__ X, const float* __restrict__ R,
    const float* __restrict__ R2, const float* __restrict__ bvec,
    const float* __restrict__ La, const float* __restrict__ Lb,
    const float* __restrict__ g, const float* __restrict__ beta,
    float* __restrict__ out, bf16* __restrict__ out2) {
  const int row = blockIdx.x;
  const int tid = threadIdx.x;

  float v[4];
  float s1 = 0.0f, s2 = 0.0f;
#pragma unroll
  for (int i = 0; i < 4; ++i) {
    const int c = tid + i * 256;
    float x = X[(size_t)row * DMODEL + c];
    if (MERGE) {
      const int h = c >> 6;
      const float rl =
          1.0f / (La[(size_t)h * S_LEN + row] + Lb[(size_t)h * S_LEN + row]);
      x += (R[(size_t)row * DMODEL + c] + R2[(size_t)row * DMODEL + c]) * rl;
    } else if (SUM2) {
      x += R[(size_t)row * DMODEL + c] + R2[(size_t)row * DMODEL + c] + bvec[c];
    } else {
      x += R[(size_t)row * DMODEL + c];
    }
    v[i] = x;
    s1 += x;
    s2 += x * x;
  }
#pragma unroll
  for (int off = 32; off; off >>= 1) {
    s1 += __shfl_xor(s1, off, 64);
    s2 += __shfl_xor(s2, off, 64);
  }
  __shared__ float w1s[4], w2s[4];
  const int wid = tid >> 6, lane = tid & 63;
  if (lane == 0) { w1s[wid] = s1; w2s[wid] = s2; }
  __syncthreads();
  s1 = w1s[0] + w1s[1] + w1s[2] + w1s[3];
  s2 = w2s[0] + w2s[1] + w2s[2] + w2s[3];

  const float mu = s1 * (1.0f / DMODEL);
  const float var = s2 * (1.0f / DMODEL) - mu * mu;
  const float rstd = rsqrtf(var + 1e-5f);

#pragma unroll
  for (int i = 0; i < 4; ++i) {
    const int c = tid + i * 256;
    const float r = (v[i] - mu) * rstd * g[c] + beta[c];
    out[(size_t)row * DMODEL + c] = r;
    if (DUAL) out2[(size_t)row * DMODEL + c] = __float2bfloat16(r);
  }
}

// ---------------------------------------------------------------------------
extern "C" void kernel_launch(void* const* d_in, const int* in_sizes, int n_in,
                              void* d_out, int out_size, void* d_ws, size_t ws_size,
                              hipStream_t stream) {
  const float* y      = (const float*)d_in[0];
  const float* enc    = (const float*)d_in[1];
  const float* Wself  = (const float*)d_in[2];
  const float* bself  = (const float*)d_in[3];
  const float* Wcross = (const float*)d_in[4];
  const float* bcross = (const float*)d_in[5];
  const float* g1     = (const float*)d_in[6];
  const float* be1    = (const float*)d_in[7];
  const float* g2     = (const float*)d_in[8];
  const float* be2    = (const float*)d_in[9];
  const float* g3     = (const float*)d_in[10];
  const float* be3    = (const float*)d_in[11];
  const float* w1     = (const float*)d_in[12];
  const float* b1     = (const float*)d_in[13];
  const float* w2     = (const float*)d_in[14];
  const float* b2     = (const float*)d_in[15];
  float* out = (float*)d_out;

  char* ws = (char*)d_ws;
  const size_t MB = 1024 * 1024;
  bf16*  ybf   = (bf16*)(ws + 0 * MB);
  bf16*  encbf = (bf16*)(ws + 4 * MB);
  float* PA    = (float*)(ws + 0 * MB);
  float* PB    = (float*)(ws + 8 * MB);
  float* Y1    = (float*)(ws + 16 * MB);
  float* Y2    = (float*)(ws + 24 * MB);
  bf16*  Q12b  = (bf16*)(ws + 32 * MB);
  bf16*  Q1t   = (bf16*)(ws + 36 * MB);
  bf16*  K2b   = (bf16*)(ws + 40 * MB);
  bf16*  K2t   = (bf16*)(ws + 44 * MB);
  bf16*  w1t   = (bf16*)(ws + 48 * MB);
  bf16*  w2t   = (bf16*)(ws + 56 * MB);
  bf16*  Wst   = (bf16*)(ws + 64 * MB);
  bf16*  Wct   = (bf16*)(ws + 66 * MB);
  bf16*  Y1bf  = (bf16*)(ws + 68 * MB);
  bf16*  Y2bf  = (bf16*)(ws + 72 * MB);
  float* La    = (float*)(ws + 76 * MB);
  float* Lb    = (float*)(ws + 76 * MB + 512 * 1024);
  bf16*  FFH   = (bf16*)(ws + 0 * MB);    // 16 MB, overlays dead PA+PB
  float* FFa   = (float*)(ws + 32 * MB);  // overlays dead Q12b+Q1t
  float* FFb   = (float*)(ws + 40 * MB);  // overlays dead K2b+K2t

  const dim3 blk(256);
  const dim3 gT_w(DMODEL / 32, DMODEL / 32, 2);
  const dim3 gT_w1(HIDDEN / 32, DMODEL / 32);
  const dim3 gT_w2(DMODEL / 32, HIDDEN / 32);
  const dim3 gConv(S_LEN * DMODEL / 4 / 256, 1, 2);
  const dim3 gProj2(DMODEL / 64, S_LEN / 64, 2);   // 1024 blocks
  const dim3 gProj(DMODEL / 64, S_LEN / 32);       // 1024 (BM=32)
  const dim3 gFf1(HIDDEN / 64, S_LEN / 64);        // 2048
  const dim3 gFf2(DMODEL / 64, S_LEN / 64, 2);     // 1024 (split-K)
  const dim3 gAttn(S_LEN / 64, NHEAD, 2);          // 1024 x 256thr (split-K)
  const dim3 gLn(S_LEN);

  // --- conversions ---
  transp_bf16_kernel<true><<<gT_w, blk, 0, stream>>>(
      Wself, Wst, Wcross, Wct, DMODEL, DMODEL);
  transp_bf16_kernel<false><<<gT_w1, blk, 0, stream>>>(
      w1, w1t, nullptr, nullptr, DMODEL, HIDDEN);
  transp_bf16_kernel<false><<<gT_w2, blk, 0, stream>>>(
      w2, w2t, nullptr, nullptr, HIDDEN, DMODEL);
  conv_bf16_kernel<<<gConv, blk, 0, stream>>>(
      y, ybf, enc, encbf, S_LEN * DMODEL / 4);

  // 1+4) Q1 = y@Wself+bself ; K2 = enc@Wcross+bcross  (dual C+C^T, one launch)
  mfma_gemm_kernel<64, 64, false, true, bf16><<<gProj2, blk, 0, stream>>>(
      ybf, Wst, bself, Q12b, Q1t,
      encbf, Wct, bcross, K2b, K2t, S_LEN, DMODEL, DMODEL, DMODEL);
  // 2) self-attention (causal), k=v=Q1; unnormalized partials
  mfma_attn_kernel<<<gAttn, blk, 0, stream>>>(
      Q12b, Q12b, Q1t, PA, PB, La, Lb, 1);
  // 3) y1 = LN(y + (PA+PB)/(La+Lb))  (+ bf16 copy)
  add_ln_kernel<true, true, false><<<gLn, blk, 0, stream>>>(
      y, PA, PB, nullptr, La, Lb, g1, be1, Y1, Y1bf);
  // 5) Q2 = y1 @ Wcross + bcross  (BM=32: 1024 blocks)
  mfma_gemm_kernel<32, 64, false, false, bf16><<<gProj, blk, 0, stream>>>(
      Y1bf, Wct, bcross, Q12b, nullptr,
      nullptr, nullptr, nullptr, nullptr, nullptr, S_LEN, DMODEL, DMODEL, DMODEL);
  // 6) cross-attention (full), k=v=K2
  mfma_attn_kernel<<<gAttn, blk, 0, stream>>>(
      Q12b, K2b, K2t, PA, PB, La, Lb, 0);
  // 7) y2 = LN(y1 + (PA+PB)/(La+Lb))  (+ bf16 copy)
  add_ln_kernel<true, true, false><<<gLn, blk, 0, stream>>>(
      Y1, PA, PB, nullptr, La, Lb, g2, be2, Y2, Y2bf);
  // 8) ffh = relu(y2 @ w1 + b1) -> bf16  (64x64: 2048 blocks)
  mfma_gemm_kernel<64, 64, true, false, bf16><<<gFf1, blk, 0, stream>>>(
      Y2bf, w1t, b1, FFH, nullptr,
      nullptr, nullptr, nullptr, nullptr, nullptr, S_LEN, HIDDEN, DMODEL, DMODEL);
  // 9) split-K FFN2
  mfma_gemm_kernel<64, 64, false, false, float><<<gFf2, blk, 0, stream>>>(
      FFH, w2t, nullptr, FFa, nullptr,
      FFH + HIDDEN / 2, w2t + HIDDEN / 2, nullptr, FFb, nullptr,
      S_LEN, DMODEL, HIDDEN, HIDDEN / 2);
  // 10) out = LN(y2 + FFa + FFb + b2)
  add_ln_kernel<false, false, true><<<gLn, blk, 0, stream>>>(
      Y2, FFa, FFb, b2, nullptr, nullptr, g3, be3, out, nullptr);
}